// Round 8
// baseline (180.646 us; speedup 1.0000x reference)
//
#include <hip/hip_runtime.h>

// ---------------------------------------------------------------------------
// DeltaModel: B=256, L=2048, H=V=64.
//  (1) hs/k/v/q depend only on token id (V=64) -> 64-entry tables.
//  (2) r = M_N q -> backward scan: for j=1..2047 (t=2047-j):
//        s_j = y^{(j-1)}[c_j];  y += s_j*(-G[:,c_j]);  r += s_j*v[c_j]
//  (3) Cost model fitted over 7 rounds: readlane of a FRESHLY-written VGPR
//      costs ~35cy (VALU->readlane hazard); stale readlane ~5cy; and >15
//      outstanding ds_reads forces lgkmcnt drains (4-bit counter).
//      This kernel: LAG-3 expansion so the chain readlane reads STALE y:
//        s_j = fmaf(cf1,s_{j-1}, fmaf(cf2,s_{j-2}, fmaf(cf3,s_{j-3}, p_j)))
//        p_j = readlane(y^{(j-4)}, c_j)   [y last written a full step ago]
//      cf_w = -G(c_j,c_{j-w}) from a wave-parallel pre-pass (float4 LDS
//      table, uniform ds_read_b128/step, zero cross-lane). y/r updates run
//      at lag 3. Exact reference fma sequence per component (same nesting,
//      oldest-first) -> bit-identical output. Col ring: 10 slots, refill
//      distance 5, static indices via 50-step super-iterations; <=14 ds
//      outstanding -> no drains. Tokens: R7 pk packing (0.2 rfl/step).
// ---------------------------------------------------------------------------

#define DPP_ADD_F32(x, ctrl, rm, bm, bc)                                      \
  (x) = (x) + __int_as_float(__builtin_amdgcn_update_dpp(                     \
            0, __float_as_int(x), (ctrl), (rm), (bm), (bc)))

__device__ __forceinline__ float wave_sum64(float x) {
  DPP_ADD_F32(x, 0x111, 0xf, 0xf, true);   // row_shr:1
  DPP_ADD_F32(x, 0x112, 0xf, 0xf, true);   // row_shr:2
  DPP_ADD_F32(x, 0x114, 0xf, 0xf, true);   // row_shr:4
  DPP_ADD_F32(x, 0x118, 0xf, 0xf, true);   // row_shr:8
  DPP_ADD_F32(x, 0x142, 0xa, 0xf, false);  // row_bcast:15
  DPP_ADD_F32(x, 0x143, 0xc, 0xf, false);  // row_bcast:31 -> lane 63 total
  return __int_as_float(__builtin_amdgcn_readlane(__float_as_int(x), 63));
}

__device__ __forceinline__ float readlane_f(float x, int lane) {
  return __int_as_float(__builtin_amdgcn_readlane(__float_as_int(x), lane));
}

// ---------------------------------------------------------------------------
// Kernel A: per-token tables k_n, v, q (weights staged in padded LDS).
// ---------------------------------------------------------------------------
__global__ __launch_bounds__(64) void build_tables(
    const float* __restrict__ embed, const float* __restrict__ W1,
    const float* __restrict__ b1, const float* __restrict__ W2,
    const float* __restrict__ b2, const float* __restrict__ gamma,
    const float* __restrict__ beta, const float* __restrict__ Wk,
    const float* __restrict__ Wv, const float* __restrict__ Wq,
    float* __restrict__ k_tab, float* __restrict__ v_tab,
    float* __restrict__ q_tab) {
  __shared__ float Wbuf[8448];
  __shared__ float e_s[64];
  __shared__ float f1_s[128];
  __shared__ float hs_s[64];
  const int tok = blockIdx.x;
  const int l = threadIdx.x;

  const float e = embed[tok * 64 + l];
  e_s[l] = e;
  for (int i = 0; i < 128; ++i) Wbuf[i * 65 + l] = W1[i * 64 + l];
  __syncthreads();

  float a0 = b1[l], a1 = b1[l + 64];
#pragma unroll
  for (int h = 0; h < 64; ++h) {
    a0 = fmaf(e_s[h], Wbuf[l * 65 + h], a0);
    a1 = fmaf(e_s[h], Wbuf[(l + 64) * 65 + h], a1);
  }
  f1_s[l] = fmaxf(a0, 0.f);
  f1_s[l + 64] = fmaxf(a1, 0.f);
  __syncthreads();

  for (int i = 0; i < 128; ++i)
    Wbuf[(i >> 1) * 131 + (i & 1) * 64 + l] = W2[i * 64 + l];
  __syncthreads();

  float acc = b2[l];
#pragma unroll
  for (int j = 0; j < 128; ++j) acc = fmaf(f1_s[j], Wbuf[l * 131 + j], acc);
  const float hval = e + acc;

  const float mu = wave_sum64(hval) * (1.f / 64.f);
  const float d = hval - mu;
  const float var = wave_sum64(d * d) * (1.f / 64.f);
  const float hs = d * (1.f / sqrtf(var + 1e-5f)) * gamma[l] + beta[l];
  hs_s[l] = hs;
  __syncthreads();

  for (int i = 0; i < 64; ++i) {
    Wbuf[i * 65 + l] = Wk[i * 64 + l];
    Wbuf[4224 + i * 65 + l] = Wv[i * 64 + l];
  }
  __syncthreads();
  float kk = 0.f, vv = 0.f;
#pragma unroll
  for (int h = 0; h < 64; ++h) {
    kk = fmaf(hs_s[h], Wbuf[l * 65 + h], kk);
    vv = fmaf(hs_s[h], Wbuf[4224 + l * 65 + h], vv);
  }
  __syncthreads();
  for (int i = 0; i < 64; ++i) Wbuf[i * 65 + l] = Wq[i * 64 + l];
  __syncthreads();
  float qq = 0.f;
#pragma unroll
  for (int h = 0; h < 64; ++h) qq = fmaf(hs_s[h], Wbuf[l * 65 + h], qq);

  float nrm = fmaxf(sqrtf(wave_sum64(kk * kk)), 1e-12f);
  k_tab[tok * 64 + l] = kk / nrm;
  v_tab[tok * 64 + l] = vv;
  q_tab[tok * 64 + l] = qq;
}

// ---------------------------------------------------------------------------
// Kernel B: GV[a][l] = {-G[a][l], v[a][l]} packed float2 (G NEGATED so every
// downstream update is a positive fma); KQ[a][l] = q_a.k_l.
// ---------------------------------------------------------------------------
__global__ __launch_bounds__(64) void build_gram(
    const float* __restrict__ k_tab, const float* __restrict__ q_tab,
    const float* __restrict__ v_tab, float2* __restrict__ GV,
    float* __restrict__ KQ) {
  __shared__ float k_s[4160];
  __shared__ float q_s[64];
  const int a = blockIdx.x;
  const int l = threadIdx.x;
  for (int i = 0; i < 64; ++i) k_s[i * 65 + l] = k_tab[i * 64 + l];
  q_s[l] = q_tab[a * 64 + l];
  __syncthreads();
  float g = 0.f, kq = 0.f;
#pragma unroll
  for (int h = 0; h < 64; ++h) {
    g = fmaf(k_s[a * 65 + h], k_s[l * 65 + h], g);
    kq = fmaf(q_s[h], k_s[l * 65 + h], kq);
  }
  GV[a * 64 + l] = make_float2(-g, v_tab[a * 64 + l]);
  KQ[a * 64 + l] = kq;
}

// ---------------------------------------------------------------------------
// Kernel B2: pack 5 six-bit tokens per 32-bit word, in scan order.
// word w of batch b holds tokens for steps j = 5w+1 .. 5w+5 (t = 2047-j).
// ---------------------------------------------------------------------------
__global__ __launch_bounds__(256) void pack_tokens(const int* __restrict__ seq,
                                                   int* __restrict__ pk) {
  const int idx = blockIdx.x * 256 + threadIdx.x;  // global word index
  const int b = idx / 410, w = idx - b * 410;
  const int* tp = seq + b * 2048;
  int acc = 0;
#pragma unroll
  for (int i = 0; i < 5; ++i) {
    const int j = 5 * w + 1 + i;
    const int t = (j <= 2047) ? tp[2047 - j] : 0;
    acc |= t << (6 * i);
  }
  pk[b * 412 + w] = acc;
}

// ---------------------------------------------------------------------------
// Kernel C: per-batch scan + head. One wave per batch, grid 256.
// ---------------------------------------------------------------------------
// One 5-step phase. P = absolute phase index (runtime ok), P5 = phase index
// within the 50-step super-iteration (LITERAL 0..9 -> static ring slots).
// CFc = coef buffer to consume (fetched last phase), CFn = fetch target.
#define PHASE(P, P5, CFc, CFn)                                                \
  {                                                                           \
    const int JB_ = 5 * (P) + 1;                                              \
    _Pragma("unroll") for (int i5 = 0; i5 < 5; ++i5) CFn[i5] =                \
        coef_s[JB_ + 5 + i5];                                                 \
    vwr[((P5) % 5 + 2) % 5] = pk_s[(P) + 7];                                  \
    _Pragma("unroll") for (int i5 = 0; i5 < 5; ++i5) {                        \
      const float pj = readlane_f(y, S[(P5) % 5][i5]);                        \
      const float2 cY = c[(5 * (P5) + i5 + 7) % 10];                          \
      c[(5 * (P5) + i5 + 5) % 10] =                                           \
          GV_s[S[((P5) % 5 + 1) % 5][i5] * 64 + l];                           \
      y = fmaf(s3, cY.x, y);                                                  \
      r = fmaf(s3, cY.y, r);                                                  \
      const float4 cf_ = CFc[i5];                                             \
      const float sj_ =                                                       \
          fmaf(cf_.x, s1, fmaf(cf_.y, s2, fmaf(cf_.z, s3, pj)));              \
      s3 = s2;                                                                \
      s2 = s1;                                                                \
      s1 = sj_;                                                               \
    }                                                                         \
    {                                                                         \
      const int u_ = __builtin_amdgcn_readfirstlane(vwr[(P5) % 5]);           \
      _Pragma("unroll") for (int i5 = 0; i5 < 5; ++i5) S[(P5) % 5][i5] =      \
          (u_ >> (6 * i5)) & 63;                                              \
    }                                                                         \
  }

__global__ __launch_bounds__(64, 1) void scan_head(
    const int* __restrict__ seq, const float2* __restrict__ GVg,
    const float* __restrict__ KQ, const int* __restrict__ pk,
    const float* __restrict__ Wrp, const float* __restrict__ brp,
    const float* __restrict__ Wout, const float* __restrict__ bout,
    float* __restrict__ out) {
  __shared__ float2 GV_s[4160];    // cols; later reused as head weight buffer
  __shared__ float4 coef_s[2064];  // per-step {cf1,cf2,cf3,-}; 2048..2063 = 0
  __shared__ int pk_s[448];        // packed tokens (410 used, rest zero)
  __shared__ float tmp[64];
  const int b = blockIdx.x;
  const int l = threadIdx.x;

#pragma unroll
  for (int i = 0; i < 32; ++i)
    ((float4*)GV_s)[l + 64 * i] = ((const float4*)GVg)[l + 64 * i];
  GV_s[4096 + l] = make_float2(0.f, 0.f);
  const int* pkb = pk + b * 412;
#pragma unroll
  for (int i = 0; i < 7; ++i) {
    const int idx = l + 64 * i;
    pk_s[idx] = (idx < 410) ? pkb[idx] : 0;
  }
  __syncthreads();

  const int* tokp = seq + b * 2048;

  // ---- coef pre-pass (wave-parallel): coef[j] = {-G(c_j,c_{j-1..3})} ----
  for (int it = 0; it < 32; ++it) {
    const int j = it * 64 + l;
    float c1 = 0.f, c2 = 0.f, c3 = 0.f;
    if (j >= 1) {
      const int t0 = tokp[2047 - j];
      const int t1 = (j >= 2) ? tokp[2048 - j] : 64;
      const int t2 = (j >= 3) ? tokp[2049 - j] : 64;
      const int t3 = (j >= 4) ? tokp[2050 - j] : 64;
      if (t1 < 64) c1 = GV_s[t0 * 64 + t1].x;
      if (t2 < 64) c2 = GV_s[t0 * 64 + t2].x;
      if (t3 < 64) c3 = GV_s[t0 * 64 + t3].x;
    }
    coef_s[j] = make_float4(c1, c2, c3, 0.f);
  }
  if (l < 16) coef_s[2048 + l] = make_float4(0.f, 0.f, 0.f, 0.f);
  __syncthreads();

  const int qt = tokp[2047];  // t=2047 token -> q
  float y = KQ[qt * 64 + l];  // y_a = k_a . q
  float r = 0.f;
  float s1 = 0.f, s2 = 0.f, s3 = 0.f;  // s_{j-1}, s_{j-2}, s_{j-3}

  // ---- token sets S[k] (subgroups, 5 tokens each) + vw word ring --------
  int S[5][5];
  int vwr[5];
#pragma unroll
  for (int k = 0; k < 5; ++k) {
    const int u = __builtin_amdgcn_readfirstlane(pk_s[k]);
#pragma unroll
    for (int i = 0; i < 5; ++i) S[k][i] = (u >> (6 * i)) & 63;
  }
  vwr[0] = pk_s[5];
  vwr[1] = pk_s[6];
  vwr[2] = 0;
  vwr[3] = 0;
  vwr[4] = 0;

  // ---- col ring: slot(col_m) = (m-1)%10. Prime m=-2..0 zero, m=1..5 load.
  float2 c[10];
  c[7] = make_float2(0.f, 0.f);
  c[8] = make_float2(0.f, 0.f);
  c[9] = make_float2(0.f, 0.f);
#pragma unroll
  for (int i = 0; i < 5; ++i) c[i] = GV_s[S[0][i] * 64 + l];

  // ---- coef buffer prime: phase 0 (steps 1..5) ---------------------------
  float4 cfA[5], cfB[5];
#pragma unroll
  for (int i = 0; i < 5; ++i) cfA[i] = coef_s[1 + i];

  // ---- main loop: 40 super-iters x 10 phases x 5 steps = j=1..2000 -------
  for (int MM = 0; MM < 40; ++MM) {
    const int P0 = 10 * MM;
    PHASE(P0 + 0, 0, cfA, cfB);
    PHASE(P0 + 1, 1, cfB, cfA);
    PHASE(P0 + 2, 2, cfA, cfB);
    PHASE(P0 + 3, 3, cfB, cfA);
    PHASE(P0 + 4, 4, cfA, cfB);
    PHASE(P0 + 5, 5, cfB, cfA);
    PHASE(P0 + 6, 6, cfA, cfB);
    PHASE(P0 + 7, 7, cfB, cfA);
    PHASE(P0 + 8, 8, cfA, cfB);
    PHASE(P0 + 9, 9, cfB, cfA);
  }
  // ---- trailer: phases 400..408 (j=2001..2045) ---------------------------
  PHASE(400, 0, cfA, cfB);
  PHASE(401, 1, cfB, cfA);
  PHASE(402, 2, cfA, cfB);
  PHASE(403, 3, cfB, cfA);
  PHASE(404, 4, cfA, cfB);
  PHASE(405, 5, cfB, cfA);
  PHASE(406, 6, cfA, cfB);
  PHASE(407, 7, cfB, cfA);
  PHASE(408, 8, cfA, cfB);

  // ---- final steps j=2046, 2047 (phase 409 = P5 9, consumes cfB) ---------
  {
    // j=2046: slotY = (45+0+7)%10 = 2 (col_2043)
    const float p0 = readlane_f(y, S[4][0]);
    const float2 cY0 = c[2];
    y = fmaf(s3, cY0.x, y);  // apply s_2043 (needed by p at j=2047)
    r = fmaf(s3, cY0.y, r);
    const float4 cf0 = cfB[0];
    const float sj0 = fmaf(cf0.x, s1, fmaf(cf0.y, s2, fmaf(cf0.z, s3, p0)));
    s3 = s2;
    s2 = s1;
    s1 = sj0;
  }
  {
    // j=2047: slotY = (45+1+7)%10 = 3 (col_2044); y-update skipped (y dead)
    const float p1 = readlane_f(y, S[4][1]);
    const float2 cY1 = c[3];
    r = fmaf(s3, cY1.y, r);  // s_2044 * v_2044
    const float4 cf1 = cfB[1];
    const float sj1 = fmaf(cf1.x, s1, fmaf(cf1.y, s2, fmaf(cf1.z, s3, p1)));
    s3 = s2;
    s2 = s1;
    s1 = sj1;
  }
  // ---- epilogue: r += s_2045 v_2045 + s_2046 v_2046 + s_2047 v_2047 ------
  r = fmaf(s3, c[4].y, r);  // col_2045: slot (2045-1)%10 = 4
  r = fmaf(s2, c[5].y, r);  // col_2046
  r = fmaf(s1, c[6].y, r);  // col_2047

  // ---- Head: r -> Wrp -> Wout (weights staged padded into GV_s memory) --
  float* Wb = (float*)GV_s;
  tmp[l] = r;
  __syncthreads();
  for (int i = 0; i < 64; ++i) {
    Wb[i * 65 + l] = Wrp[i * 64 + l];
    Wb[4160 + i * 65 + l] = Wout[i * 64 + l];
  }
  __syncthreads();
  float acc = brp[l];
#pragma unroll
  for (int j = 0; j < 64; ++j) acc = fmaf(tmp[j], Wb[l * 65 + j], acc);
  __syncthreads();
  tmp[l] = acc;
  __syncthreads();
  float o = bout[l];
#pragma unroll
  for (int i = 0; i < 64; ++i) o = fmaf(tmp[i], Wb[4160 + l * 65 + i], o);
  out[b * 64 + l] = o;
}

extern "C" void kernel_launch(void* const* d_in, const int* in_sizes, int n_in,
                              void* d_out, int out_size, void* d_ws,
                              size_t ws_size, hipStream_t stream) {
  const int* seq = (const int*)d_in[0];
  const float* embed = (const float*)d_in[1];
  const float* W1 = (const float*)d_in[2];
  const float* b1 = (const float*)d_in[3];
  const float* W2 = (const float*)d_in[4];
  const float* b2 = (const float*)d_in[5];
  const float* gamma = (const float*)d_in[6];
  const float* beta = (const float*)d_in[7];
  const float* Wk = (const float*)d_in[8];
  const float* Wv = (const float*)d_in[9];
  const float* Wq = (const float*)d_in[10];
  const float* Wrp = (const float*)d_in[11];
  const float* brp = (const float*)d_in[12];
  const float* Wout = (const float*)d_in[13];
  const float* bout = (const float*)d_in[14];

  float* wsf = (float*)d_ws;
  float* k_tab = wsf;                   // 4096
  float* v_tab = wsf + 4096;            // 4096
  float* q_tab = wsf + 8192;            // 4096
  float2* GV = (float2*)(wsf + 12288);  // 4096 float2 = 8192 floats
  float* KQ = wsf + 20480;              // 4096
  int* pk = (int*)(wsf + 24576);        // 256 * 412 ints

  build_tables<<<64, 64, 0, stream>>>(embed, W1, b1, W2, b2, gamma, beta, Wk,
                                      Wv, Wq, k_tab, v_tab, q_tab);
  build_gram<<<64, 64, 0, stream>>>(k_tab, q_tab, v_tab, GV, KQ);
  pack_tokens<<<410, 256, 0, stream>>>(seq, pk);
  scan_head<<<256, 64, 0, stream>>>(seq, GV, KQ, pk, Wrp, brp, Wout, bout,
                                    (float*)d_out);
}

// Round 9
// 170.210 us; speedup vs baseline: 1.0613x; 1.0613x over previous
//
#include <hip/hip_runtime.h>

// ---------------------------------------------------------------------------
// DeltaModel: B=256, L=2048, H=V=64.
//  (1) hs/k/v/q depend only on token id (V=64) -> 64-entry tables.
//  (2) r = M_N q -> backward scan: for j=1..2047 (t=2047-j):
//        s_j = y^{(j-1)}[c_j];  y += s_j*(-G[:,c_j]);  r += s_j*v[c_j]
//  (3) Model after 8 rounds: v_readlane's VALU->SGPR writeback stalls wave
//      issue ~30-40cy, un-overlappable (R6: 2 chains = 2x RT). Fix: keep
//      broadcasts in the VGPR/LDS domain via ds_bpermute (uniform addr =
//      broadcast, result VGPR, lgkm-counted ASYNC -> latency hideable).
//      Lookahead-1 identity (bit-exact, proven R4):
//        s_j = fmaf(cf_j, s_{j-1}, yb_j)          chain = ONE fma
//        yb_j = bpermute(y^{(j-2)}, c_j*4)        issued 2 steps early
//        cf_j = -G(c_j, c_{j-1})                  uniform LDS read, 2 early
//      G table padded to 65-wide rows; slot 64 and row 64 zeroed so the
//      dummy step-0 token (64) yields cf=0 / zero column. Token broadcasts
//      by bpermute of the token vector (static lane consts), 8 ahead.
//      ZERO cross-lane->SGPR ops in the main loop.
// ---------------------------------------------------------------------------

#define DPP_ADD_F32(x, ctrl, rm, bm, bc)                                      \
  (x) = (x) + __int_as_float(__builtin_amdgcn_update_dpp(                     \
            0, __float_as_int(x), (ctrl), (rm), (bm), (bc)))

__device__ __forceinline__ float wave_sum64(float x) {
  DPP_ADD_F32(x, 0x111, 0xf, 0xf, true);   // row_shr:1
  DPP_ADD_F32(x, 0x112, 0xf, 0xf, true);   // row_shr:2
  DPP_ADD_F32(x, 0x114, 0xf, 0xf, true);   // row_shr:4
  DPP_ADD_F32(x, 0x118, 0xf, 0xf, true);   // row_shr:8
  DPP_ADD_F32(x, 0x142, 0xa, 0xf, false);  // row_bcast:15
  DPP_ADD_F32(x, 0x143, 0xc, 0xf, false);  // row_bcast:31 -> lane 63 total
  return __int_as_float(__builtin_amdgcn_readlane(__float_as_int(x), 63));
}

__device__ __forceinline__ float bperm_f(int byte_addr, float v) {
  return __int_as_float(
      __builtin_amdgcn_ds_bpermute(byte_addr, __float_as_int(v)));
}

// ---------------------------------------------------------------------------
// Kernel A: per-token tables k_n, v, q (weights staged in padded LDS).
// ---------------------------------------------------------------------------
__global__ __launch_bounds__(64) void build_tables(
    const float* __restrict__ embed, const float* __restrict__ W1,
    const float* __restrict__ b1, const float* __restrict__ W2,
    const float* __restrict__ b2, const float* __restrict__ gamma,
    const float* __restrict__ beta, const float* __restrict__ Wk,
    const float* __restrict__ Wv, const float* __restrict__ Wq,
    float* __restrict__ k_tab, float* __restrict__ v_tab,
    float* __restrict__ q_tab) {
  __shared__ float Wbuf[8448];
  __shared__ float e_s[64];
  __shared__ float f1_s[128];
  __shared__ float hs_s[64];
  const int tok = blockIdx.x;
  const int l = threadIdx.x;

  const float e = embed[tok * 64 + l];
  e_s[l] = e;
  for (int i = 0; i < 128; ++i) Wbuf[i * 65 + l] = W1[i * 64 + l];
  __syncthreads();

  float a0 = b1[l], a1 = b1[l + 64];
#pragma unroll
  for (int h = 0; h < 64; ++h) {
    a0 = fmaf(e_s[h], Wbuf[l * 65 + h], a0);
    a1 = fmaf(e_s[h], Wbuf[(l + 64) * 65 + h], a1);
  }
  f1_s[l] = fmaxf(a0, 0.f);
  f1_s[l + 64] = fmaxf(a1, 0.f);
  __syncthreads();

  for (int i = 0; i < 128; ++i)
    Wbuf[(i >> 1) * 131 + (i & 1) * 64 + l] = W2[i * 64 + l];
  __syncthreads();

  float acc = b2[l];
#pragma unroll
  for (int j = 0; j < 128; ++j) acc = fmaf(f1_s[j], Wbuf[l * 131 + j], acc);
  const float hval = e + acc;

  const float mu = wave_sum64(hval) * (1.f / 64.f);
  const float d = hval - mu;
  const float var = wave_sum64(d * d) * (1.f / 64.f);
  const float hs = d * (1.f / sqrtf(var + 1e-5f)) * gamma[l] + beta[l];
  hs_s[l] = hs;
  __syncthreads();

  for (int i = 0; i < 64; ++i) {
    Wbuf[i * 65 + l] = Wk[i * 64 + l];
    Wbuf[4224 + i * 65 + l] = Wv[i * 64 + l];
  }
  __syncthreads();
  float kk = 0.f, vv = 0.f;
#pragma unroll
  for (int h = 0; h < 64; ++h) {
    kk = fmaf(hs_s[h], Wbuf[l * 65 + h], kk);
    vv = fmaf(hs_s[h], Wbuf[4224 + l * 65 + h], vv);
  }
  __syncthreads();
  for (int i = 0; i < 64; ++i) Wbuf[i * 65 + l] = Wq[i * 64 + l];
  __syncthreads();
  float qq = 0.f;
#pragma unroll
  for (int h = 0; h < 64; ++h) qq = fmaf(hs_s[h], Wbuf[l * 65 + h], qq);

  float nrm = fmaxf(sqrtf(wave_sum64(kk * kk)), 1e-12f);
  k_tab[tok * 64 + l] = kk / nrm;
  v_tab[tok * 64 + l] = vv;
  q_tab[tok * 64 + l] = qq;
}

// ---------------------------------------------------------------------------
// Kernel B: GV[a][l] = {-G[a][l], v[a][l]} packed float2 (G NEGATED so every
// downstream update is a positive fma); KQ[a][l] = q_a.k_l.
// ---------------------------------------------------------------------------
__global__ __launch_bounds__(64) void build_gram(
    const float* __restrict__ k_tab, const float* __restrict__ q_tab,
    const float* __restrict__ v_tab, float2* __restrict__ GV,
    float* __restrict__ KQ) {
  __shared__ float k_s[4160];
  __shared__ float q_s[64];
  const int a = blockIdx.x;
  const int l = threadIdx.x;
  for (int i = 0; i < 64; ++i) k_s[i * 65 + l] = k_tab[i * 64 + l];
  q_s[l] = q_tab[a * 64 + l];
  __syncthreads();
  float g = 0.f, kq = 0.f;
#pragma unroll
  for (int h = 0; h < 64; ++h) {
    g = fmaf(k_s[a * 65 + h], k_s[l * 65 + h], g);
    kq = fmaf(q_s[h], k_s[l * 65 + h], kq);
  }
  GV[a * 64 + l] = make_float2(-g, v_tab[a * 64 + l]);
  KQ[a * 64 + l] = kq;
}

// ---------------------------------------------------------------------------
// Kernel C: per-batch scan + head. One wave per batch, grid 256.
// Rings (all static indices, fully unrolled 64-step body):
//   cbR[8]  token broadcasts (bpermute), target j+8
//   t65R[4] row base c_t*65, computed when col for target t+? flows through
//   colR[4] GV column for target j (issued at j-4)
//   cfR[4]  cf_t = -G(c_t, c_{t-1}) uniform read (issued at t-2)
//   ybR[4]  yb_t = bpermute(y^{(t-2)}, c_t*4) (issued at t-2, post-update)
// Per step: 4 DS ops, ~14 VALU ops; chain = one fma.
// ---------------------------------------------------------------------------
__global__ __launch_bounds__(64, 1) void scan_head(
    const int* __restrict__ seq, const float2* __restrict__ GVg,
    const float* __restrict__ KQ, const float* __restrict__ Wrp,
    const float* __restrict__ brp, const float* __restrict__ Wout,
    const float* __restrict__ bout, float* __restrict__ out) {
  __shared__ float2 GV_s[4225];  // 65x65: row t at t*65; row 64 + slot 64 = 0
  __shared__ float tmp[64];
  const int b = blockIdx.x;
  const int l = threadIdx.x;

  for (int t = 0; t < 64; ++t) GV_s[t * 65 + l] = GVg[t * 64 + l];
  GV_s[64 * 65 + l] = make_float2(0.f, 0.f);  // dummy row 64
  GV_s[l * 65 + 64] = make_float2(0.f, 0.f);  // slot-64 pad of rows 0..63
  if (l == 0) GV_s[64 * 65 + 64] = make_float2(0.f, 0.f);
  __syncthreads();

  const int* tokp = seq + b * 2048;
  const int qt = tokp[2047];  // t=2047 token -> q
  float y = KQ[qt * 64 + l];  // y_a = k_a . q
  float r = 0.f;

  // token vectors: lane j holds token of step 64*blk + j (plain 0..63; 64 =
  // dummy). Step 0 = dummy (q position).
  int tok_cur = (l == 0) ? 64 : tokp[2047 - l];  // block 0
  int tok_nxt = tokp[2047 - 64 - l];             // block 1

  int cbR[8];
  int t65R[4];
  float2 colR[4];
  float cfR[4];
  float ybR[4];

  // ---- priming ----------------------------------------------------------
#pragma unroll
  for (int t = 0; t < 8; ++t)
    cbR[t] = __builtin_amdgcn_ds_bpermute(4 * t, tok_cur);
#pragma unroll
  for (int t = 0; t < 4; ++t) colR[t] = GV_s[cbR[t] * 65 + l];
  t65R[2] = cbR[2] * 65;  // row base for cf target 2 (used at step 0)
  t65R[3] = cbR[3] * 65;  // row base for cf target 3 (used at step 1)
  cfR[0] = 0.f;                               // step 0: no predecessor
  cfR[1] = GV_s[cbR[1] * 65 + cbR[0]].x;      // c_0 = 64 -> slot 64 = 0
  ybR[0] = bperm_f((cbR[0] & 63) << 2, y);    // reads y_init (dummy step)
  ybR[1] = bperm_f((cbR[1] & 63) << 2, y);    // y^(−1) = y_init (step0 noop)
  float s_prev = 0.f;
  int idxv = 32;  // bcast addr = 4*((j+8)&63), starts at target 8

  // ---- main loop: 32 blocks x 64 steps ----------------------------------
  for (int blk = 0; blk < 32; ++blk) {
    const int tok_fut =
        (blk + 2 < 32) ? tokp[2047 - 64 * (blk + 2) - l] : 64;
#pragma unroll
    for (int j = 0; j < 64; ++j) {
      // token broadcast for step j+8 (source select is compile-time)
      cbR[j & 7] =
          __builtin_amdgcn_ds_bpermute(idxv, (j < 56) ? tok_cur : tok_nxt);
      idxv = (j == 55) ? 0 : idxv + 4;
      // consume this step's column BEFORE overwriting its ring slot
      const float2 gv = colR[j & 3];
      // column + row-base for step j+4
      const int t65 = cbR[(j + 4) & 7] * 65;
      t65R[(j + 4) & 3] = t65;
      colR[j & 3] = GV_s[t65 + l];
      // cf for step j+2: -G(c_{j+2}, c_{j+1})  (uniform read, slot-64 safe)
      cfR[(j + 2) & 3] = GV_s[t65R[(j + 2) & 3] + cbR[(j + 1) & 7]].x;
      // chain: ONE fma  (bit-exact: fmaf(s_{j-1}, -G, y^{(j-2)}[c_j]))
      const float sj = fmaf(cfR[j & 3], s_prev, ybR[j & 3]);
      // y/r updates (reference order)
      y = fmaf(sj, gv.x, y);
      r = fmaf(sj, gv.y, r);
      // yb for step j+2: broadcast of y^{(j)} at lane c_{j+2}
      ybR[(j + 2) & 3] = bperm_f((cbR[(j + 2) & 7] & 63) << 2, y);
      s_prev = sj;
    }
    tok_cur = tok_nxt;
    tok_nxt = tok_fut;
  }

  // ---- Head: r -> Wrp -> Wout (weights staged padded into GV_s memory) --
  float* Wb = (float*)GV_s;
  tmp[l] = r;
  __syncthreads();
  for (int i = 0; i < 64; ++i) {
    Wb[i * 65 + l] = Wrp[i * 64 + l];
    Wb[4160 + i * 65 + l] = Wout[i * 64 + l];
  }
  __syncthreads();
  float acc = brp[l];
#pragma unroll
  for (int j = 0; j < 64; ++j) acc = fmaf(tmp[j], Wb[l * 65 + j], acc);
  __syncthreads();
  tmp[l] = acc;
  __syncthreads();
  float o = bout[l];
#pragma unroll
  for (int i = 0; i < 64; ++i) o = fmaf(tmp[i], Wb[4160 + l * 65 + i], o);
  out[b * 64 + l] = o;
}

extern "C" void kernel_launch(void* const* d_in, const int* in_sizes, int n_in,
                              void* d_out, int out_size, void* d_ws,
                              size_t ws_size, hipStream_t stream) {
  const int* seq = (const int*)d_in[0];
  const float* embed = (const float*)d_in[1];
  const float* W1 = (const float*)d_in[2];
  const float* b1 = (const float*)d_in[3];
  const float* W2 = (const float*)d_in[4];
  const float* b2 = (const float*)d_in[5];
  const float* gamma = (const float*)d_in[6];
  const float* beta = (const float*)d_in[7];
  const float* Wk = (const float*)d_in[8];
  const float* Wv = (const float*)d_in[9];
  const float* Wq = (const float*)d_in[10];
  const float* Wrp = (const float*)d_in[11];
  const float* brp = (const float*)d_in[12];
  const float* Wout = (const float*)d_in[13];
  const float* bout = (const float*)d_in[14];

  float* wsf = (float*)d_ws;
  float* k_tab = wsf;                   // 4096
  float* v_tab = wsf + 4096;            // 4096
  float* q_tab = wsf + 8192;            // 4096
  float2* GV = (float2*)(wsf + 12288);  // 4096 float2 = 8192 floats
  float* KQ = wsf + 20480;              // 4096

  build_tables<<<64, 64, 0, stream>>>(embed, W1, b1, W2, b2, gamma, beta, Wk,
                                      Wv, Wq, k_tab, v_tab, q_tab);
  build_gram<<<64, 64, 0, stream>>>(k_tab, q_tab, v_tab, GV, KQ);
  scan_head<<<256, 64, 0, stream>>>(seq, GV, KQ, Wrp, brp, Wout, bout,
                                    (float*)d_out);
}